// Round 8
// baseline (342.751 us; speedup 1.0000x reference)
//
#include <hip/hip_runtime.h>

// Problem constants (match reference setup_inputs)
constexpr int NN = 100000;   // nodes
constexpr int NE = 1600000;  // edges
constexpr int NG = 128;      // graphs

constexpr int BLK = 256;
constexpr int NE4 = NE / 4;
constexpr int G_RANK = (NE4 + BLK - 1) / BLK;   // 1563
constexpr int G_N    = (NN + BLK - 1) / BLK;    // 391

constexpr int SCAN_T = 256;
constexpr int SCAN_B = (NN + SCAN_T - 1) / SCAN_T;  // 391

// interleaved CSR entry: src index + raw edge weight (norm folded into pulls)
struct __align__(8) Ent { int s; float nw; };

// ---------------- front kernel: rank (atomics) ∥ layer-1 mm4 ∥ bounds ----------------

__global__ void k_front(const int4* __restrict__ dst4, int* __restrict__ cnt,
                        ushort4* __restrict__ rank4,
                        const float* __restrict__ x, const float* __restrict__ W1,
                        float* __restrict__ T,
                        const int* __restrict__ batch, int* __restrict__ gstart) {
    __shared__ float sW[4 * 32 * 8];
    int b = blockIdx.x;
    if (b < G_RANK) {
        // ---- rank: the only atomic pass (4 edges/thread) ----
        int i = b * BLK + threadIdx.x;
        if (i >= NE4) return;
        int4 d = dst4[i];
        ushort4 r;
        r.x = (ushort)atomicAdd(&cnt[d.x], 1);
        r.y = (ushort)atomicAdd(&cnt[d.y], 1);
        r.z = (ushort)atomicAdd(&cnt[d.z], 1);
        r.w = (ushort)atomicAdd(&cnt[d.w], 1);
        rank4[i] = r;
    } else if (b < G_RANK + G_N) {
        // ---- layer-1 mm4: T[k] = x @ W1[k] (k=3 scaled later in k_degi) ----
        for (int i = threadIdx.x; i < 4 * 32 * 8; i += BLK) sW[i] = W1[i];
        __syncthreads();
        int n = (b - G_RANK) * BLK + threadIdx.x;
        if (n >= NN) return;
        float hr[32];
        const float4* hp = reinterpret_cast<const float4*>(x + (size_t)n * 32);
#pragma unroll
        for (int f = 0; f < 8; ++f) {
            float4 v = hp[f];
            hr[4 * f] = v.x; hr[4 * f + 1] = v.y; hr[4 * f + 2] = v.z; hr[4 * f + 3] = v.w;
        }
#pragma unroll
        for (int k = 0; k < 4; ++k) {
            float acc[8];
#pragma unroll
            for (int j = 0; j < 8; ++j) acc[j] = 0.f;
#pragma unroll
            for (int i = 0; i < 32; ++i) {
                float hv = hr[i];
                const float* wrow = &sW[(k * 32 + i) * 8];
#pragma unroll
                for (int j = 0; j < 8; ++j) acc[j] = fmaf(hv, wrow[j], acc[j]);
            }
            float4* op = reinterpret_cast<float4*>(T + ((size_t)k * NN + n) * 8);
            op[0] = make_float4(acc[0], acc[1], acc[2], acc[3]);
            op[1] = make_float4(acc[4], acc[5], acc[6], acc[7]);
        }
    } else {
        // ---- graph segment bounds (batch is sorted) ----
        int i = (b - G_RANK - G_N) * BLK + threadIdx.x;
        if (i >= NN) return;
        int bb = batch[i];
        int prev = (i == 0) ? -1 : batch[i - 1];
        for (int g = prev + 1; g <= bb; ++g) gstart[g] = i;
        if (i == NN - 1) {
            for (int g = bb + 1; g <= NG; ++g) gstart[g] = NN;
        }
    }
}

// ---- multi-block exclusive scan of PADDED counts -> row_ptr (segments even) ----

__global__ void k_scan1(const int* __restrict__ cnt, int* __restrict__ bsum, int nn) {
    __shared__ int s[SCAN_T];
    int i = blockIdx.x * SCAN_T + threadIdx.x;
    s[threadIdx.x] = (i < nn) ? ((cnt[i] + 1) & ~1) : 0;
    __syncthreads();
    for (int off = SCAN_T / 2; off > 0; off >>= 1) {
        if (threadIdx.x < off) s[threadIdx.x] += s[threadIdx.x + off];
        __syncthreads();
    }
    if (threadIdx.x == 0) bsum[blockIdx.x] = s[0];
}

__global__ void k_scan2(int* __restrict__ bsum, int nb) {
    __shared__ int s[512];
    int t = threadIdx.x;
    s[t] = (t < nb) ? bsum[t] : 0;
    __syncthreads();
    for (int off = 1; off < 512; off <<= 1) {
        int v = (t >= off) ? s[t - off] : 0;
        __syncthreads();
        s[t] += v;
        __syncthreads();
    }
    if (t < nb) bsum[t] = (t > 0) ? s[t - 1] : 0;
}

// phase 3 + fused pad entry for odd-degree nodes
__global__ void k_scan3(const int* __restrict__ cnt, const int* __restrict__ bsum,
                        int* __restrict__ row_ptr, Ent* __restrict__ csr, int nn) {
    __shared__ int s[SCAN_T];
    int t = threadIdx.x;
    int i = blockIdx.x * SCAN_T + t;
    int c0 = (i < nn) ? cnt[i] : 0;
    int v = (c0 + 1) & ~1;
    s[t] = v;
    __syncthreads();
    for (int off = 1; off < SCAN_T; off <<= 1) {
        int u = (t >= off) ? s[t - off] : 0;
        __syncthreads();
        s[t] += u;
        __syncthreads();
    }
    int incl = s[t];
    int base = bsum[blockIdx.x];
    if (i < nn) {
        int rp = base + incl - v;
        row_ptr[i] = rp;
        if (i == nn - 1) row_ptr[nn] = base + incl;
        if (c0 & 1) {  // zero pad entry (exact no-op in all sums)
            Ent z; z.s = 0; z.nw = 0.f;
            csr[rp + c0] = z;
        }
    }
}

// atomic-free scatter into CSR slots (4 edges/thread)
__global__ void k_scatter2(const int4* __restrict__ src4, const int4* __restrict__ dst4,
                           const float4* __restrict__ w4, const int* __restrict__ row_ptr,
                           const ushort4* __restrict__ rank4, Ent* __restrict__ csr, int ne4) {
    int i = blockIdx.x * blockDim.x + threadIdx.x;
    if (i >= ne4) return;
    int4 s = src4[i]; int4 d = dst4[i]; float4 w = w4[i]; ushort4 r = rank4[i];
    Ent e0; e0.s = s.x; e0.nw = w.x; csr[row_ptr[d.x] + r.x] = e0;
    Ent e1; e1.s = s.y; e1.nw = w.y; csr[row_ptr[d.y] + r.y] = e1;
    Ent e2; e2.s = s.z; e2.nw = w.z; csr[row_ptr[d.z] + r.z] = e2;
    Ent e3; e3.s = s.w; e3.nw = w.w; csr[row_ptr[d.w] + r.w] = e3;
}

// weighted in-degree -> dinv, fused T3 *= dinv (8 lanes per node)
__global__ void k_degi(const int* __restrict__ row_ptr, const float4* __restrict__ csr4,
                       float* __restrict__ dinv, float4* __restrict__ T3, int nn) {
    int tid = blockIdx.x * blockDim.x + threadIdx.x;
    int n = tid >> 3, lane = tid & 7;
    if (n >= nn) return;
    int beg = row_ptr[n] >> 1, end = row_ptr[n + 1] >> 1;  // pair units
    float s = 0.f;
    for (int p = beg + lane; p < end; p += 8) {
        float4 a = csr4[p];
        s += a.y + a.w;
    }
    s += __shfl_xor(s, 1, 64);
    s += __shfl_xor(s, 2, 64);
    s += __shfl_xor(s, 4, 64);   // all 8 lanes now hold the group sum
    float dv = s > 0.f ? rsqrtf(fmaxf(s, 1e-30f)) : 0.f;
    if (lane == 0) dinv[n] = dv;
    if (lane < 2) {  // scale T3 row (2 float4 chunks)
        float4 t = T3[(size_t)n * 2 + lane];
        T3[(size_t)n * 2 + lane] = make_float4(t.x * dv, t.y * dv, t.z * dv, t.w * dv);
    }
}

// ---------------- fused 4-way dense mm (layer 2): U[k] = h1 @ W2[k]; k==3 pre-scaled ----
__global__ void k_mm4b(const float* __restrict__ h, const float* __restrict__ W,
                       const float* __restrict__ dinv, float* __restrict__ t, int nn) {
    __shared__ float sW[4 * 8 * 16];
    for (int i = threadIdx.x; i < 4 * 8 * 16; i += blockDim.x) sW[i] = W[i];
    __syncthreads();
    int n = blockIdx.x * blockDim.x + threadIdx.x;
    if (n >= nn) return;
    float hr[8];
    const float4* hp = reinterpret_cast<const float4*>(h + (size_t)n * 8);
#pragma unroll
    for (int f = 0; f < 2; ++f) {
        float4 v = hp[f];
        hr[4 * f] = v.x; hr[4 * f + 1] = v.y; hr[4 * f + 2] = v.z; hr[4 * f + 3] = v.w;
    }
    float dv = dinv[n];
#pragma unroll
    for (int k = 0; k < 4; ++k) {
        float acc[16];
#pragma unroll
        for (int j = 0; j < 16; ++j) acc[j] = 0.f;
#pragma unroll
        for (int i = 0; i < 8; ++i) {
            float hv = hr[i];
            const float* wrow = &sW[(k * 8 + i) * 16];
#pragma unroll
            for (int j = 0; j < 16; ++j) acc[j] = fmaf(hv, wrow[j], acc[j]);
        }
        if (k == 3) {
#pragma unroll
            for (int j = 0; j < 16; ++j) acc[j] *= dv;
        }
        float4* op = reinterpret_cast<float4*>(t + ((size_t)k * nn + n) * 16);
#pragma unroll
        for (int j4 = 0; j4 < 4; ++j4)
            op[j4] = make_float4(acc[4 * j4], acc[4 * j4 + 1], acc[4 * j4 + 2], acc[4 * j4 + 3]);
    }
}

// ---------------- pull propagate (float4 gathers; F/4 lanes per node) ----------------
// MID:   hout = dinv[d] * (dinv[d]*Sum + add[d])
// FINAL: hout = relu(dinv[d]*Sum + add[d] + b)
template <int F, bool FINAL>
__global__ void k_pull(const int* __restrict__ row_ptr, const float4* __restrict__ csr4,
                       const float* __restrict__ dinv,
                       const float4* __restrict__ hin4, const float4* __restrict__ add4,
                       const float* __restrict__ b, float4* __restrict__ hout4, int nn) {
    constexpr int P = F / 4;  // lanes per node, each owns one float4 chunk
    int g = blockIdx.x * (blockDim.x / P) + threadIdx.x / P;
    int c = threadIdx.x & (P - 1);
    if (g >= nn) return;
    int p = row_ptr[g] >> 1, end = row_ptr[g + 1] >> 1;  // pair units (segments even)
    float4 A = make_float4(0.f, 0.f, 0.f, 0.f);
    float4 B = make_float4(0.f, 0.f, 0.f, 0.f);
    for (; p < end; ++p) {
        float4 a = csr4[p];
        int s0 = __float_as_int(a.x), s1 = __float_as_int(a.z);
        float4 h0 = hin4[(size_t)s0 * P + c];
        float4 h1 = hin4[(size_t)s1 * P + c];
        A.x = fmaf(h0.x, a.y, A.x); A.y = fmaf(h0.y, a.y, A.y);
        A.z = fmaf(h0.z, a.y, A.z); A.w = fmaf(h0.w, a.y, A.w);
        B.x = fmaf(h1.x, a.w, B.x); B.y = fmaf(h1.y, a.w, B.y);
        B.z = fmaf(h1.z, a.w, B.z); B.w = fmaf(h1.w, a.w, B.w);
    }
    float dv = dinv[g];
    float4 ad = add4[(size_t)g * P + c];
    float4 r;
    if (FINAL) {
        float4 bb = reinterpret_cast<const float4*>(b)[c];
        r.x = fmaxf(dv * (A.x + B.x) + ad.x + bb.x, 0.f);
        r.y = fmaxf(dv * (A.y + B.y) + ad.y + bb.y, 0.f);
        r.z = fmaxf(dv * (A.z + B.z) + ad.z + bb.z, 0.f);
        r.w = fmaxf(dv * (A.w + B.w) + ad.w + bb.w, 0.f);
    } else {
        r.x = dv * (dv * (A.x + B.x) + ad.x);
        r.y = dv * (dv * (A.y + B.y) + ad.y);
        r.z = dv * (dv * (A.z + B.z) + ad.z);
        r.w = dv * (dv * (A.w + B.w) + ad.w);
    }
    hout4[(size_t)g * P + c] = r;
}

// ---------------- pooling + fused FC (batch sorted -> contiguous segments) ----------------

__global__ void k_pool2(const float* __restrict__ h, const int* __restrict__ start,
                        const float* __restrict__ Wfc, const float* __restrict__ bfc,
                        float* __restrict__ out) {
    int g = blockIdx.x;
    int beg = start[g], end = start[g + 1];
    int tid = threadIdx.x;
    int feat = tid & 15, grp = tid >> 4;  // 16 node-groups x 16 features
    float mx = 0.f, sm = 0.f;  // post-ReLU values are >= 0
    for (int n = beg + grp; n < end; n += 16) {
        float v = h[(size_t)n * 16 + feat];
        mx = fmaxf(mx, v);
        sm += v;
    }
    mx = fmaxf(mx, __shfl_xor(mx, 16, 64));
    sm += __shfl_xor(sm, 16, 64);
    mx = fmaxf(mx, __shfl_xor(mx, 32, 64));
    sm += __shfl_xor(sm, 32, 64);
    __shared__ float smx[4][16], ssm[4][16];
    int wave = tid >> 6;
    int lane = tid & 63;
    if (lane < 16) { smx[wave][feat] = mx; ssm[wave][feat] = sm; }
    __syncthreads();
    if (tid < 16) {
        float m = fmaxf(fmaxf(smx[0][tid], smx[1][tid]), fmaxf(smx[2][tid], smx[3][tid]));
        float s = ssm[0][tid] + ssm[1][tid] + ssm[2][tid] + ssm[3][tid];
        smx[0][tid] = m;
        ssm[0][tid] = (end > beg) ? s / (float)(end - beg) : 0.f;
    }
    __syncthreads();
    if (tid < 2) {
        float acc = bfc[tid];
#pragma unroll
        for (int i = 0; i < 16; ++i) acc += smx[0][i] * Wfc[i * 2 + tid];
#pragma unroll
        for (int i = 0; i < 16; ++i) acc += ssm[0][i] * Wfc[(16 + i) * 2 + tid];
        out[g * 2 + tid] = acc;
    }
}

// ---------------- launch ----------------

extern "C" void kernel_launch(void* const* d_in, const int* in_sizes, int n_in,
                              void* d_out, int out_size, void* d_ws, size_t ws_size,
                              hipStream_t stream) {
    const float* x    = (const float*)d_in[0];           // NN x 32
    const int*   eidx = (const int*)d_in[1];             // 2 x NE
    const int*   srcp = eidx;
    const int*   dstp = eidx + NE;
    const int*   batch= (const int*)d_in[2];             // NN
    const float* ew   = (const float*)d_in[3];           // NE
    const float* W1   = (const float*)d_in[4];           // 4 x 32 x 8
    const float* b1   = (const float*)d_in[5];           // 8
    const float* W2   = (const float*)d_in[6];           // 4 x 8 x 16
    const float* b2   = (const float*)d_in[7];           // 16
    const float* Wfc  = (const float*)d_in[8];           // 32 x 2
    const float* bfc  = (const float*)d_in[9];           // 2
    float* out = (float*)d_out;                          // NG x 2

    constexpr size_t NN8  = (size_t)NN * 8;
    constexpr size_t NN16 = (size_t)NN * 16;

    // workspace layout (4-byte units; csr & uni kept 16B-aligned)
    float*  dinv    = (float*)d_ws;               // NN
    int*    cnt     = (int*)(dinv + NN);          // NN
    int*    row_ptr = cnt + NN;                   // NN + 4
    ushort* rank    = (ushort*)(row_ptr + NN + 4);// NE ushorts
    Ent*    csr     = (Ent*)((int*)(void*)rank + NE / 2);  // NE+NN entries
    float*  uni     = (float*)(csr + NE + NN);    // union region
    float*  h1      = uni + 5 * NN16;             // NN*8
    int*    gstart  = (int*)(h1 + NN8);           // NG+1
    int*    bsum    = gstart + NG + 4;            // SCAN_B

    // layer-1 aliases: T = 4 x NN8, P, P2
    float* T  = uni;
    float* P  = uni + 2 * NN16;
    float* P2 = P + NN8;
    // layer-2 aliases: U = 4 x NN16, q, q2/out2 reuse dead u-slots
    float* U    = uni;
    float* q    = uni + 4 * NN16;
    float* q2   = U + 3 * NN16;   // u3 slot (dead after hop 1)
    float* out2 = U + 2 * NN16;   // u2 slot (dead after hop 1)

    const float4* csr4 = (const float4*)csr;

    const int gP8  = (NN + (BLK / 2) - 1) / (BLK / 2);   // pull F=8: 2 lanes/node
    const int gP16 = (NN + (BLK / 4) - 1) / (BLK / 4);   // pull F=16: 4 lanes/node
    const int gN8  = (NN * 8 + BLK - 1) / BLK;

    // ---- front: rank atomics ∥ layer-1 mm4 ∥ bounds ----
    hipMemsetAsync(cnt, 0, (size_t)NN * sizeof(int), stream);
    k_front<<<G_RANK + 2 * G_N, BLK, 0, stream>>>((const int4*)dstp, cnt, (ushort4*)rank,
                                                  x, W1, T, batch, gstart);
    // ---- CSR finish ----
    k_scan1<<<SCAN_B, SCAN_T, 0, stream>>>(cnt, bsum, NN);
    k_scan2<<<1, 512, 0, stream>>>(bsum, SCAN_B);
    k_scan3<<<SCAN_B, SCAN_T, 0, stream>>>(cnt, bsum, row_ptr, csr, NN);
    k_scatter2<<<G_RANK, BLK, 0, stream>>>((const int4*)srcp, (const int4*)dstp,
                                           (const float4*)ew, row_ptr, (const ushort4*)rank,
                                           csr, NE4);
    k_degi<<<gN8, BLK, 0, stream>>>(row_ptr, csr4, dinv, (float4*)(T + 3 * NN8), NN);

    // ---- layer 1 (Horner, dinv-folded): propagate at F=8 ----
    k_pull<8, false><<<gP8, BLK, 0, stream>>>(row_ptr, csr4, dinv, (const float4*)(T + 3 * NN8),
                                              (const float4*)(T + 2 * NN8), nullptr, (float4*)P, NN);
    k_pull<8, false><<<gP8, BLK, 0, stream>>>(row_ptr, csr4, dinv, (const float4*)P,
                                              (const float4*)(T + 1 * NN8), nullptr, (float4*)P2, NN);
    k_pull<8, true ><<<gP8, BLK, 0, stream>>>(row_ptr, csr4, dinv, (const float4*)P2,
                                              (const float4*)T, b1, (float4*)h1, NN);

    // ---- layer 2 (Horner, dinv-folded): propagate at F=16 ----
    k_mm4b<<<G_N, BLK, 0, stream>>>(h1, W2, dinv, U, NN);
    k_pull<16, false><<<gP16, BLK, 0, stream>>>(row_ptr, csr4, dinv, (const float4*)(U + 3 * NN16),
                                                (const float4*)(U + 2 * NN16), nullptr, (float4*)q, NN);
    k_pull<16, false><<<gP16, BLK, 0, stream>>>(row_ptr, csr4, dinv, (const float4*)q,
                                                (const float4*)(U + 1 * NN16), nullptr, (float4*)q2, NN);
    k_pull<16, true ><<<gP16, BLK, 0, stream>>>(row_ptr, csr4, dinv, (const float4*)q2,
                                                (const float4*)U, b2, (float4*)out2, NN);

    // ---- pooling + fused FC (no atomics) ----
    k_pool2<<<NG, 256, 0, stream>>>(out2, gstart, Wfc, bfc, out);
}

// Round 9
// 305.339 us; speedup vs baseline: 1.1225x; 1.1225x over previous
//
#include <hip/hip_runtime.h>

// Problem constants (match reference setup_inputs)
constexpr int NN = 100000;   // nodes
constexpr int NE = 1600000;  // edges
constexpr int NG = 128;      // graphs

constexpr int SCAN_T = 256;
constexpr int SCAN_B = (NN + SCAN_T - 1) / SCAN_T;  // 391

// interleaved CSR entry: src index + raw edge weight (norm folded into pulls)
struct __align__(8) Ent { int s; float nw; };

// ---------------- CSR build ----------------

// the only atomic pass: in-degree count + per-edge rank (4 edges/thread)
__global__ void k_rank(const int4* __restrict__ dst4, int* __restrict__ cnt,
                       ushort4* __restrict__ rank4, int ne4) {
    int i = blockIdx.x * blockDim.x + threadIdx.x;
    if (i >= ne4) return;
    int4 d = dst4[i];
    ushort4 r;
    r.x = (ushort)atomicAdd(&cnt[d.x], 1);
    r.y = (ushort)atomicAdd(&cnt[d.y], 1);
    r.z = (ushort)atomicAdd(&cnt[d.z], 1);
    r.w = (ushort)atomicAdd(&cnt[d.w], 1);
    rank4[i] = r;
}

// ---- multi-block exclusive scan of PADDED counts -> row_ptr (segments even) ----
// phase 1 fused with graph-bounds computation (homogeneous tiny blocks)
__global__ void k_scan1b(const int* __restrict__ cnt, int* __restrict__ bsum,
                         const int* __restrict__ batch, int* __restrict__ gstart, int nn) {
    __shared__ int s[SCAN_T];
    int b = blockIdx.x;
    if (b < SCAN_B) {
        int i = b * SCAN_T + threadIdx.x;
        s[threadIdx.x] = (i < nn) ? ((cnt[i] + 1) & ~1) : 0;
        __syncthreads();
        for (int off = SCAN_T / 2; off > 0; off >>= 1) {
            if (threadIdx.x < off) s[threadIdx.x] += s[threadIdx.x + off];
            __syncthreads();
        }
        if (threadIdx.x == 0) bsum[b] = s[0];
    } else {
        // graph segment bounds (batch is sorted)
        int i = (b - SCAN_B) * SCAN_T + threadIdx.x;
        if (i >= nn) return;
        int bb = batch[i];
        int prev = (i == 0) ? -1 : batch[i - 1];
        for (int g = prev + 1; g <= bb; ++g) gstart[g] = i;
        if (i == nn - 1) {
            for (int g = bb + 1; g <= NG; ++g) gstart[g] = nn;
        }
    }
}

__global__ void k_scan2(int* __restrict__ bsum, int nb) {
    __shared__ int s[512];
    int t = threadIdx.x;
    s[t] = (t < nb) ? bsum[t] : 0;
    __syncthreads();
    for (int off = 1; off < 512; off <<= 1) {
        int v = (t >= off) ? s[t - off] : 0;
        __syncthreads();
        s[t] += v;
        __syncthreads();
    }
    if (t < nb) bsum[t] = (t > 0) ? s[t - 1] : 0;
}

// phase 3 + fused zero-pad entry for odd-degree nodes
__global__ void k_scan3(const int* __restrict__ cnt, const int* __restrict__ bsum,
                        int* __restrict__ row_ptr, Ent* __restrict__ csr, int nn) {
    __shared__ int s[SCAN_T];
    int t = threadIdx.x;
    int i = blockIdx.x * SCAN_T + t;
    int c0 = (i < nn) ? cnt[i] : 0;
    int v = (c0 + 1) & ~1;
    s[t] = v;
    __syncthreads();
    for (int off = 1; off < SCAN_T; off <<= 1) {
        int u = (t >= off) ? s[t - off] : 0;
        __syncthreads();
        s[t] += u;
        __syncthreads();
    }
    int incl = s[t];
    int base = bsum[blockIdx.x];
    if (i < nn) {
        int rp = base + incl - v;
        row_ptr[i] = rp;
        if (i == nn - 1) row_ptr[nn] = base + incl;
        if (c0 & 1) {  // zero pad entry (exact no-op in all sums)
            Ent z; z.s = 0; z.nw = 0.f;
            csr[rp + c0] = z;
        }
    }
}

// atomic-free scatter into CSR slots (4 edges/thread)
__global__ void k_scatter2(const int4* __restrict__ src4, const int4* __restrict__ dst4,
                           const float4* __restrict__ w4, const int* __restrict__ row_ptr,
                           const ushort4* __restrict__ rank4, Ent* __restrict__ csr, int ne4) {
    int i = blockIdx.x * blockDim.x + threadIdx.x;
    if (i >= ne4) return;
    int4 s = src4[i]; int4 d = dst4[i]; float4 w = w4[i]; ushort4 r = rank4[i];
    Ent e0; e0.s = s.x; e0.nw = w.x; csr[row_ptr[d.x] + r.x] = e0;
    Ent e1; e1.s = s.y; e1.nw = w.y; csr[row_ptr[d.y] + r.y] = e1;
    Ent e2; e2.s = s.z; e2.nw = w.z; csr[row_ptr[d.z] + r.z] = e2;
    Ent e3; e3.s = s.w; e3.nw = w.w; csr[row_ptr[d.w] + r.w] = e3;
}

// weighted in-degree from CSR segments -> dinv; 8 lanes per node, float4 loads
__global__ void k_degi(const int* __restrict__ row_ptr, const float4* __restrict__ csr4,
                       float* __restrict__ dinv, int nn) {
    int tid = blockIdx.x * blockDim.x + threadIdx.x;
    int n = tid >> 3, lane = tid & 7;
    if (n >= nn) return;
    int beg = row_ptr[n] >> 1, end = row_ptr[n + 1] >> 1;  // pair units
    float s = 0.f;
    for (int p = beg + lane; p < end; p += 8) {
        float4 a = csr4[p];
        s += a.y + a.w;
    }
    s += __shfl_xor(s, 1, 64);
    s += __shfl_xor(s, 2, 64);
    s += __shfl_xor(s, 4, 64);
    if (lane == 0) dinv[n] = s > 0.f ? rsqrtf(fmaxf(s, 1e-30f)) : 0.f;
}

// ---------------- fused 4-way dense mm: t[k] = h @ W[k]; k==3 output pre-scaled by dinv ----
template <int FIN, int FOUT>
__global__ void k_mm4(const float* __restrict__ h, const float* __restrict__ W,
                      const float* __restrict__ dinv, float* __restrict__ t, int nn) {
    __shared__ float sW[4 * FIN * FOUT];
    for (int i = threadIdx.x; i < 4 * FIN * FOUT; i += blockDim.x) sW[i] = W[i];
    __syncthreads();
    int n = blockIdx.x * blockDim.x + threadIdx.x;
    if (n >= nn) return;
    float hr[FIN];
    const float4* hp = reinterpret_cast<const float4*>(h + (size_t)n * FIN);
#pragma unroll
    for (int f = 0; f < FIN / 4; ++f) {
        float4 v = hp[f];
        hr[4 * f + 0] = v.x; hr[4 * f + 1] = v.y;
        hr[4 * f + 2] = v.z; hr[4 * f + 3] = v.w;
    }
    float dv = dinv[n];
#pragma unroll
    for (int k = 0; k < 4; ++k) {
        float acc[FOUT];
#pragma unroll
        for (int j = 0; j < FOUT; ++j) acc[j] = 0.f;
#pragma unroll
        for (int i = 0; i < FIN; ++i) {
            float hv = hr[i];
            const float* wrow = &sW[(k * FIN + i) * FOUT];
#pragma unroll
            for (int j = 0; j < FOUT; ++j) acc[j] = fmaf(hv, wrow[j], acc[j]);
        }
        if (k == 3) {
#pragma unroll
            for (int j = 0; j < FOUT; ++j) acc[j] *= dv;
        }
        float4* op = reinterpret_cast<float4*>(t + ((size_t)k * nn + n) * FOUT);
#pragma unroll
        for (int j4 = 0; j4 < FOUT / 4; ++j4)
            op[j4] = make_float4(acc[4 * j4], acc[4 * j4 + 1], acc[4 * j4 + 2], acc[4 * j4 + 3]);
    }
}

// ---------------- pull propagate (dinv folded; fused add / bias+relu) ----------------
// MID:   hout = dinv[d] * (dinv[d]*Sum + add[d])     (pre-scaled for next hop)
// FINAL: hout = relu(dinv[d]*Sum + add[d] + b)
template <int F, bool FINAL>
__global__ void k_pull(const int* __restrict__ row_ptr, const float4* __restrict__ csr4,
                       const float* __restrict__ dinv,
                       const float* __restrict__ hin, const float* __restrict__ add,
                       const float* __restrict__ b, float* __restrict__ hout, int nn) {
    int g = blockIdx.x * (blockDim.x / F) + threadIdx.x / F;
    int lane = threadIdx.x & (F - 1);
    if (g >= nn) return;
    int p = row_ptr[g] >> 1, end = row_ptr[g + 1] >> 1;  // pair units (segments even)
    float acc0 = 0.f, acc1 = 0.f, acc2 = 0.f, acc3 = 0.f;
    for (; p + 2 <= end; p += 2) {
        float4 a = csr4[p], c = csr4[p + 1];
        acc0 = fmaf(hin[(size_t)__float_as_int(a.x) * F + lane], a.y, acc0);
        acc1 = fmaf(hin[(size_t)__float_as_int(a.z) * F + lane], a.w, acc1);
        acc2 = fmaf(hin[(size_t)__float_as_int(c.x) * F + lane], c.y, acc2);
        acc3 = fmaf(hin[(size_t)__float_as_int(c.z) * F + lane], c.w, acc3);
    }
    if (p < end) {
        float4 a = csr4[p];
        acc0 = fmaf(hin[(size_t)__float_as_int(a.x) * F + lane], a.y, acc0);
        acc1 = fmaf(hin[(size_t)__float_as_int(a.z) * F + lane], a.w, acc1);
    }
    float acc = (acc0 + acc1) + (acc2 + acc3);
    float dv = dinv[g];
    float r;
    if (FINAL) r = fmaxf(dv * acc + add[(size_t)g * F + lane] + b[lane], 0.f);
    else       r = dv * (dv * acc + add[(size_t)g * F + lane]);
    hout[(size_t)g * F + lane] = r;
}

// ---------------- pooling + fused FC (batch sorted -> contiguous segments) ----------------

__global__ void k_pool2(const float* __restrict__ h, const int* __restrict__ start,
                        const float* __restrict__ Wfc, const float* __restrict__ bfc,
                        float* __restrict__ out) {
    int g = blockIdx.x;
    int beg = start[g], end = start[g + 1];
    int tid = threadIdx.x;
    int feat = tid & 15, grp = tid >> 4;  // 16 node-groups x 16 features
    float mx = 0.f, sm = 0.f;  // post-ReLU values are >= 0
    for (int n = beg + grp; n < end; n += 16) {
        float v = h[(size_t)n * 16 + feat];
        mx = fmaxf(mx, v);
        sm += v;
    }
    mx = fmaxf(mx, __shfl_xor(mx, 16, 64));
    sm += __shfl_xor(sm, 16, 64);
    mx = fmaxf(mx, __shfl_xor(mx, 32, 64));
    sm += __shfl_xor(sm, 32, 64);
    __shared__ float smx[4][16], ssm[4][16];
    int wave = tid >> 6;
    int lane = tid & 63;
    if (lane < 16) { smx[wave][feat] = mx; ssm[wave][feat] = sm; }
    __syncthreads();
    if (tid < 16) {
        float m = fmaxf(fmaxf(smx[0][tid], smx[1][tid]), fmaxf(smx[2][tid], smx[3][tid]));
        float s = ssm[0][tid] + ssm[1][tid] + ssm[2][tid] + ssm[3][tid];
        smx[0][tid] = m;
        ssm[0][tid] = (end > beg) ? s / (float)(end - beg) : 0.f;
    }
    __syncthreads();
    if (tid < 2) {
        float acc = bfc[tid];
#pragma unroll
        for (int i = 0; i < 16; ++i) acc += smx[0][i] * Wfc[i * 2 + tid];
#pragma unroll
        for (int i = 0; i < 16; ++i) acc += ssm[0][i] * Wfc[(16 + i) * 2 + tid];
        out[g * 2 + tid] = acc;
    }
}

// ---------------- launch ----------------

extern "C" void kernel_launch(void* const* d_in, const int* in_sizes, int n_in,
                              void* d_out, int out_size, void* d_ws, size_t ws_size,
                              hipStream_t stream) {
    const float* x    = (const float*)d_in[0];           // NN x 32
    const int*   eidx = (const int*)d_in[1];             // 2 x NE
    const int*   srcp = eidx;
    const int*   dstp = eidx + NE;
    const int*   batch= (const int*)d_in[2];             // NN
    const float* ew   = (const float*)d_in[3];           // NE
    const float* W1   = (const float*)d_in[4];           // 4 x 32 x 8
    const float* b1   = (const float*)d_in[5];           // 8
    const float* W2   = (const float*)d_in[6];           // 4 x 8 x 16
    const float* b2   = (const float*)d_in[7];           // 16
    const float* Wfc  = (const float*)d_in[8];           // 32 x 2
    const float* bfc  = (const float*)d_in[9];           // 2
    float* out = (float*)d_out;                          // NG x 2

    constexpr size_t NN8  = (size_t)NN * 8;
    constexpr size_t NN16 = (size_t)NN * 16;

    // workspace layout (4-byte units; csr & uni kept 16B-aligned)
    float*  dinv    = (float*)d_ws;               // NN
    int*    cnt     = (int*)(dinv + NN);          // NN
    int*    row_ptr = cnt + NN;                   // NN + 4
    ushort* rank    = (ushort*)(row_ptr + NN + 4);// NE ushorts
    Ent*    csr     = (Ent*)((int*)(void*)rank + NE / 2);  // NE+NN entries
    float*  uni     = (float*)(csr + NE + NN);    // union region
    float*  h1      = uni + 5 * NN16;             // NN*8
    int*    gstart  = (int*)(h1 + NN8);           // NG+1
    int*    bsum    = gstart + NG + 4;            // SCAN_B

    // layer-1 aliases: T = 4 x NN8, P, P2
    float* T  = uni;
    float* P  = uni + 2 * NN16;
    float* P2 = P + NN8;
    // layer-2 aliases: U = 4 x NN16, q, q2/out2 reuse dead u-slots
    float* U    = uni;
    float* q    = uni + 4 * NN16;
    float* q2   = U + 3 * NN16;   // u3 slot (dead after hop 1)
    float* out2 = U + 2 * NN16;   // u2 slot (dead after hop 1)

    const float4* csr4 = (const float4*)csr;

    const int BLK = 256;
    const int NE4 = NE / 4;
    const int gE4 = (NE4 + BLK - 1) / BLK;
    const int gN  = (NN + BLK - 1) / BLK;
    const int gP8  = (NN + (BLK / 8) - 1) / (BLK / 8);
    const int gP16 = (NN + (BLK / 16) - 1) / (BLK / 16);
    const int gN8  = (NN * 8 + BLK - 1) / BLK;

    // ---- CSR build (single atomic pass, raw weights; norm folded into pulls) ----
    hipMemsetAsync(cnt, 0, (size_t)NN * sizeof(int), stream);
    k_rank<<<gE4, BLK, 0, stream>>>((const int4*)dstp, cnt, (ushort4*)rank, NE4);
    k_scan1b<<<SCAN_B + gN, SCAN_T, 0, stream>>>(cnt, bsum, batch, gstart, NN);
    k_scan2<<<1, 512, 0, stream>>>(bsum, SCAN_B);
    k_scan3<<<SCAN_B, SCAN_T, 0, stream>>>(cnt, bsum, row_ptr, csr, NN);
    k_scatter2<<<gE4, BLK, 0, stream>>>((const int4*)srcp, (const int4*)dstp,
                                        (const float4*)ew, row_ptr, (const ushort4*)rank,
                                        csr, NE4);
    k_degi<<<gN8, BLK, 0, stream>>>(row_ptr, csr4, dinv, NN);

    // ---- layer 1 (Horner, dinv-folded): propagate at F=8 ----
    k_mm4<32, 8><<<gN, BLK, 0, stream>>>(x, W1, dinv, T, NN);
    k_pull<8, false><<<gP8, BLK, 0, stream>>>(row_ptr, csr4, dinv, T + 3 * NN8, T + 2 * NN8, nullptr, P, NN);
    k_pull<8, false><<<gP8, BLK, 0, stream>>>(row_ptr, csr4, dinv, P, T + 1 * NN8, nullptr, P2, NN);
    k_pull<8, true ><<<gP8, BLK, 0, stream>>>(row_ptr, csr4, dinv, P2, T, b1, h1, NN);

    // ---- layer 2 (Horner, dinv-folded): propagate at F=16 ----
    k_mm4<8, 16><<<gN, BLK, 0, stream>>>(h1, W2, dinv, U, NN);
    k_pull<16, false><<<gP16, BLK, 0, stream>>>(row_ptr, csr4, dinv, U + 3 * NN16, U + 2 * NN16, nullptr, q, NN);
    k_pull<16, false><<<gP16, BLK, 0, stream>>>(row_ptr, csr4, dinv, q, U + 1 * NN16, nullptr, q2, NN);
    k_pull<16, true ><<<gP16, BLK, 0, stream>>>(row_ptr, csr4, dinv, q2, U, b2, out2, NN);

    // ---- pooling + fused FC (no atomics) ----
    k_pool2<<<NG, 256, 0, stream>>>(out2, gstart, Wfc, bfc, out);
}